// Round 6
// baseline (48953.671 us; speedup 1.0000x reference)
//
#include <hip/hip_runtime.h>
#include <hip/hip_bf16.h>
#include <cstdint>
#include <cstddef>

// ---------------------------------------------------------------------------
// FlumenHead: encoder MLP (32->512->512->1024) + 2048-step LSTM (D=9, F=1024)
// v6: fragment-linear B everywhere (hbuf == LDS image == MFMA fragment order):
// publish = contiguous 1KB/wave, fill = identity copy (coalesced + conflict-
// free ds_write_b128), K-loop ds_read_b128 contiguous per wave (0 conflicts,
// imm offsets). 4 compute waves x 2 pinned M-tiles (Apin 256 regs -> AGPRs,
// B-frag reused by 2 MFMAs => LDS read halved); 4 helper waves do pack/
// publish/tag/h_seq off the compute path. v5 sync protocol unchanged.
// ---------------------------------------------------------------------------

typedef __bf16 bf16x8_t __attribute__((ext_vector_type(8)));
typedef float f32x4_t __attribute__((ext_vector_type(4)));
typedef int   i32x4_t __attribute__((ext_vector_type(4)));
typedef unsigned long long u64_t;
typedef unsigned long long u64x2_t __attribute__((ext_vector_type(2)));
typedef unsigned short u16x4_t __attribute__((ext_vector_type(4)));

// workspace layout (bytes); total ~18.6 MB
#define WS_TAGS    0          // int  tags[2048][32][4] (16B per (t,w))   1 MB
#define WS_HBUF    1048576    // u16  hbuf[2][128 blk][64 ln][8] bf16   256 KB
#define WS_WSHUF   1310720    // u16  Wshuf[256 mt][32 kt][64 ln][8]      8 MB
#define WS_WAUG    9699328    // u16  WaugI[256 mt][64 ln][8]           256 KB
#define WS_XHAT    9961472    // u16  Xhat[2048 t][64 b][32] bf16         8 MB
#define WS_H1      18350080   // f32  h1[64][512]                       128 KB
#define WS_H2      18481152   // f32  h2[64][512]                       128 KB

__device__ __forceinline__ unsigned short f2bf(float f) {
  unsigned int u = __float_as_uint(f);
  u = (u + 0x7fffu + ((u >> 16) & 1u)) >> 16;   // RNE
  return (unsigned short)u;
}
__device__ __forceinline__ float sigm(float x) { return 1.f / (1.f + __expf(-x)); }
__device__ __forceinline__ float tanh_f(float x) {
  float e = __expf(-2.f * fabsf(x));
  float r = (1.f - e) / (1.f + e);
  return copysignf(r, x);
}

// ---------------------------- encoder ----------------------------

__global__ void flumen_enc1(const float* __restrict__ x, const float* __restrict__ W,
                            const float* __restrict__ b, float* __restrict__ h1) {
  const int bb = blockIdx.x;   // batch 0..63
  const int o  = threadIdx.x;  // 0..511
  const f32x4_t* xr = (const f32x4_t*)(x + bb * 32);
  const f32x4_t* wr = (const f32x4_t*)(W + o * 32);
  float acc = b[o];
#pragma unroll
  for (int q = 0; q < 8; ++q) {
    f32x4_t xv = xr[q], wv = wr[q];
    acc += xv[0] * wv[0] + xv[1] * wv[1] + xv[2] * wv[2] + xv[3] * wv[3];
  }
  h1[bb * 512 + o] = fmaxf(acc, 0.f);
}

__global__ void flumen_enc2(const float* __restrict__ in, const float* __restrict__ W,
                            const float* __restrict__ bv, float* __restrict__ outb) {
  __shared__ float s[64 * 256];
  const int tid = threadIdx.x;
  const int ol = tid & 63, bg = tid >> 6;
  const int o = blockIdx.x * 64 + ol;
  float bias = bv[o];
  float acc[8];
#pragma unroll
  for (int q = 0; q < 8; ++q) acc[q] = bias;
  for (int p = 0; p < 2; ++p) {
    __syncthreads();
    for (int i = tid; i < 4096; i += 512) {
      int flat = i * 4;
      int bb = flat >> 8, kk = flat & 255;
      *(f32x4_t*)(s + flat) = *(const f32x4_t*)(in + bb * 512 + p * 256 + kk);
    }
    __syncthreads();
    for (int kk = 0; kk < 256; kk += 4) {
      f32x4_t wv = *(const f32x4_t*)(W + o * 512 + p * 256 + kk);
#pragma unroll
      for (int j = 0; j < 4; ++j) {
        float wj = wv[j];
#pragma unroll
        for (int q = 0; q < 8; ++q)
          acc[q] += wj * s[(bg * 8 + q) * 256 + kk + j];
      }
    }
  }
#pragma unroll
  for (int q = 0; q < 8; ++q)
    outb[(bg * 8 + q) * 512 + o] = fmaxf(acc[q], 0.f);
}

__global__ void flumen_enc3(const float* __restrict__ in, const float* __restrict__ W,
                            const float* __restrict__ bv, float* __restrict__ dout,
                            unsigned short* __restrict__ hbuf) {
  __shared__ float s[64 * 256];
  const int tid = threadIdx.x;
  const int ol = tid & 63, bg = tid >> 6;
  const int o = blockIdx.x * 64 + ol;   // 0..1023
  float bias = bv[o];
  float acc[8];
#pragma unroll
  for (int q = 0; q < 8; ++q) acc[q] = bias;
  for (int p = 0; p < 2; ++p) {
    __syncthreads();
    for (int i = tid; i < 4096; i += 512) {
      int flat = i * 4;
      int bb = flat >> 8, kk = flat & 255;
      *(f32x4_t*)(s + flat) = *(const f32x4_t*)(in + bb * 512 + p * 256 + kk);
    }
    __syncthreads();
    for (int kk = 0; kk < 256; kk += 4) {
      f32x4_t wv = *(const f32x4_t*)(W + o * 512 + p * 256 + kk);
#pragma unroll
      for (int j = 0; j < 4; ++j) {
        float wj = wv[j];
#pragma unroll
        for (int q = 0; q < 8; ++q)
          acc[q] += wj * s[(bg * 8 + q) * 256 + kk + j];
      }
    }
  }
  float* out_hseq = dout + 65536;
#pragma unroll
  for (int q = 0; q < 8; ++q) {
    int bb = bg * 8 + q;
    float v = acc[q];
    out_hseq[(size_t)bb * 2097152 + o] = v;   // h_seq[b][0][o]
    // fragment-linear hbuf[0]: block = (b>>4)*32 + (o>>5),
    // lane = ((o>>3)&3)*16 + (b&15), e = o&7
    int blk  = (bb >> 4) * 32 + (o >> 5);
    int lane = ((o >> 3) & 3) * 16 + (bb & 15);
    hbuf[blk * 512 + lane * 8 + (o & 7)] = f2bf(v);
  }
}

// ---------------------------- precompute ----------------------------

// Gate-interleaved A fragments: Wshuf[mt][kt][lane][8],
// A row r = lane&15 -> gate g = r&3, feature f = mt*4 + (r>>2);
// k = kt*32 + (lane>>4)*8 + e; src = w_hh[(g*1024+f)*1024 + k].
__global__ void flumen_wshuf(const float* __restrict__ src, unsigned short* __restrict__ dst) {
  int idx = blockIdx.x * 512 + threadIdx.x;      // 0..524287
  int lane = idx & 63, kt = (idx >> 6) & 31, mt = idx >> 11;
  int r = lane & 15;
  int g = r & 3, f = mt * 4 + (r >> 2);
  int k0 = kt * 32 + (lane >> 4) * 8;
  const float* sp = src + (size_t)(g * 1024 + f) * 1024 + k0;
  f32x4_t v0 = *(const f32x4_t*)(sp);
  f32x4_t v1 = *(const f32x4_t*)(sp + 4);
  u16x4_t o0, o1;
#pragma unroll
  for (int j = 0; j < 4; ++j) { o0[j] = f2bf(v0[j]); o1[j] = f2bf(v1[j]); }
  u16x4_t* dp = (u16x4_t*)(dst + (size_t)idx * 8);
  dp[0] = o0; dp[1] = o1;
}

// Gate-interleaved augmented fragments: WaugI[mt][lane][8], K=32:
// k<9 -> w_ih[(g*1024+f)*9+k], k==9 -> bias[g*1024+f], else 0.
__global__ void flumen_waugi(const float* __restrict__ wih, const float* __restrict__ bias,
                             unsigned short* __restrict__ dst) {
  int idx = blockIdx.x * 512 + threadIdx.x;      // 0..16383
  int lane = idx & 63, mt = idx >> 6;
  int r = lane & 15;
  int g = r & 3, f = mt * 4 + (r >> 2);
  int k0 = (lane >> 4) * 8;
  unsigned short o[8];
#pragma unroll
  for (int j = 0; j < 8; ++j) {
    int k = k0 + j;
    float v = (k < 9) ? wih[(size_t)(g * 1024 + f) * 9 + k]
                      : (k == 9 ? bias[g * 1024 + f] : 0.f);
    o[j] = f2bf(v);
  }
  u16x4_t* dp = (u16x4_t*)(dst + (size_t)idx * 8);
  dp[0] = *(u16x4_t*)&o[0];
  dp[1] = *(u16x4_t*)&o[4];
}

// Xhat[t][b][0..8]=x[b][t][:], [9]=1.0, rest 0. grid=2048.
__global__ void flumen_convx(const float* __restrict__ xin, unsigned short* __restrict__ dst) {
  int i = (blockIdx.x * 512 + threadIdx.x) * 4;   // elem index, 4 at a time
  int b = i >> 16, t = (i >> 5) & 2047, c0 = i & 31;
  u16x4_t o;
#pragma unroll
  for (int j = 0; j < 4; ++j) {
    int cc = c0 + j;
    float v = (cc < 9) ? xin[((size_t)b * 2048 + t) * 9 + cc] : (cc == 9 ? 1.f : 0.f);
    o[j] = f2bf(v);
  }
  *(u16x4_t*)(dst + ((size_t)t * 64 + b) * 32 + c0) = o;
}

// ---------------------------- persistent LSTM ----------------------------
// 32 WGs x 512 thr, 1 WG/CU (137 KB LDS). WG w owns features [32w,32w+32).
// Fragment-linear B: block (n,kt) at byte (n*32+kt)*1024 + lane*16 holds
// h[n*16 + (lane&15)][kt*32 + (lane>>4)*8 + e]. hbuf (global) uses the SAME
// layout -> fill is an identity copy; producer w publishes blocks kt=w.
// Waves 0-3: compute, wave cw owns M-tiles {w*8+2cw, w*8+2cw+1}, Apin[2][32]
// (256 regs -> AGPR), B-frag shared by both tiles. Waves 4-7: helpers
// (pack/publish 1KB + tag + h_seq).
__global__ __launch_bounds__(512, 1) void flumen_lstm(
    const unsigned short* __restrict__ Wshuf,
    const unsigned short* __restrict__ WaugI,
    const unsigned short* __restrict__ Xhat,
    unsigned short* hbuf, int* tags, float* out)
{
  __shared__ __align__(16) char smem[140288];
  char*  h_lds = smem;                           // 128KB fragment-linear B
  float* hs    = (float*)(smem + 131072);        // [64][36] f32 staging

  float* out_hlast = out;
  float* out_hseq  = out + 65536;
  const int w    = blockIdx.x;       // 0..31
  const int tid  = threadIdx.x;
  const int lane = tid & 63;
  const int wave = tid >> 6;         // 0..7
  const int l15  = lane & 15;
  const int l4   = lane >> 4;
  const bool is_compute = (wave < 4);
  const int cw = wave & 3;           // compute-wave id / helper id

  // pinned A (compute waves): 2 M-tiles x 32 K-frags = 256 regs (AGPR file)
  bf16x8_t Apin[2][32];
  bf16x8_t wfragI[2];
  if (is_compute) {
#pragma unroll
    for (int q = 0; q < 2; ++q) {
      const size_t mt = (size_t)(w * 8 + cw * 2 + q);
      const char* ap = (const char*)Wshuf + mt * 32768 + lane * 16;
#pragma unroll
      for (int kt = 0; kt < 32; ++kt)
        Apin[q][kt] = *(const bf16x8_t*)(ap + kt * 1024);
      wfragI[q] = *(const bf16x8_t*)((const char*)WaugI + mt * 1024 + lane * 16);
    }
  }

  float carr[2][4] = {{0.f,0.f,0.f,0.f},{0.f,0.f,0.f,0.f}};

  for (int t = 0; t < 2048; ++t) {
    f32x4_t acc[2][4];
    if (is_compute) {
      // x fragments + aug MFMAs (independent of h_t; before the poll)
#pragma unroll
      for (int n = 0; n < 4; ++n) {
        bf16x8_t xf = *(const bf16x8_t*)(Xhat + ((size_t)t * 64 + n * 16 + l15) * 32 + l4 * 8);
#pragma unroll
        for (int q = 0; q < 2; ++q)
          acc[q][n] = __builtin_amdgcn_mfma_f32_16x16x32_bf16(
              wfragI[q], xf, (f32x4_t){0.f, 0.f, 0.f, 0.f}, 0, 0, 0);
      }
    }

    if (t > 0) {
      if (lane < 32) {   // whole wave blocks (exec-mask divergence)
        const char* tp = (const char*)tags + ((size_t)(t - 1) * 32 + lane) * 16;
        int iter = 0;
        while (true) {
          i32x4_t tv;
          asm volatile("global_load_dwordx4 %0, %1, off sc1\n\ts_waitcnt vmcnt(0)"
                       : "=v"(tv) : "v"(tp) : "memory");
          bool good = (tv[0] == t) && (tv[1] == t) && (tv[2] == t) && (tv[3] == t);
          if (__all(good) || ++iter >= (1 << 20)) break;
        }
      }
      __builtin_amdgcn_sched_barrier(0);
    }

    // identity fill: hbuf[t&1] -> h_lds (coalesced + conflict-free)
    {
      const char* src0 = (const char*)hbuf + (size_t)((t & 1) * 131072) + tid * 16;
      f32x4_t v[8];
#pragma unroll
      for (int i = 0; i < 8; ++i)
        asm volatile("global_load_dwordx4 %0, %1, off sc1"
                     : "=v"(v[i]) : "v"(src0 + i * 8192) : "memory");
      asm volatile("s_waitcnt vmcnt(0)" ::: "memory");
      __builtin_amdgcn_sched_barrier(0);
#pragma unroll
      for (int i = 0; i < 8; ++i)
        *(f32x4_t*)(h_lds + tid * 16 + i * 8192) = v[i];
#pragma unroll
      for (int i = 0; i < 8; ++i)
        asm volatile("global_load_dwordx4 %0, %1, off sc1"
                     : "=v"(v[i]) : "v"(src0 + (i + 8) * 8192) : "memory");
      asm volatile("s_waitcnt vmcnt(0)" ::: "memory");
      __builtin_amdgcn_sched_barrier(0);
#pragma unroll
      for (int i = 0; i < 8; ++i)
        *(f32x4_t*)(h_lds + tid * 16 + (i + 8) * 8192) = v[i];
    }
    __syncthreads();

    if (is_compute) {
      // K loop: B-frag read once, feeds both M-tiles
#pragma unroll
      for (int n = 0; n < 4; ++n) {
        const char* bb = h_lds + n * 32768 + lane * 16;
#pragma unroll
        for (int kt = 0; kt < 32; ++kt) {
          bf16x8_t bf = *(const bf16x8_t*)(bb + kt * 1024);
          acc[0][n] = __builtin_amdgcn_mfma_f32_16x16x32_bf16(Apin[0][kt], bf, acc[0][n], 0, 0, 0);
          acc[1][n] = __builtin_amdgcn_mfma_f32_16x16x32_bf16(Apin[1][kt], bf, acc[1][n], 0, 0, 0);
        }
      }
      // lane-local cell update: acc[q][n] = {i,f,g,o} of
      // (batch n*16+l15, feat w*32 + (cw*2+q)*4 + l4)
#pragma unroll
      for (int q = 0; q < 2; ++q)
#pragma unroll
        for (int n = 0; n < 4; ++n) {
          float c = sigm(acc[q][n][1]) * carr[q][n] + sigm(acc[q][n][0]) * tanh_f(acc[q][n][2]);
          carr[q][n] = c;
          float h = sigm(acc[q][n][3]) * tanh_f(c);
          if (t < 2047) {
            hs[(n * 16 + l15) * 36 + (cw * 2 + q) * 4 + l4] = h;
          } else {
            out_hlast[(n * 16 + l15) * 1024 + w * 32 + (cw * 2 + q) * 4 + l4] = h;
          }
        }
    }
    __syncthreads();

    if (!is_compute && t < 2047) {
      // helper hw = cw: publish block (hw*32 + w): 1KB contiguous, sc1
      const int b = cw * 16 + l15;
      f32x4_t u0 = *(const f32x4_t*)(hs + b * 36 + l4 * 8);
      f32x4_t u1 = *(const f32x4_t*)(hs + b * 36 + l4 * 8 + 4);
      u64_t lo = (u64_t)f2bf(u0[0]) | ((u64_t)f2bf(u0[1]) << 16)
               | ((u64_t)f2bf(u0[2]) << 32) | ((u64_t)f2bf(u0[3]) << 48);
      u64_t hi = (u64_t)f2bf(u1[0]) | ((u64_t)f2bf(u1[1]) << 16)
               | ((u64_t)f2bf(u1[2]) << 32) | ((u64_t)f2bf(u1[3]) << 48);
      u64x2_t q = {lo, hi};
      char* dst = (char*)hbuf + (size_t)(((t + 1) & 1) * 131072)
                + (cw * 32 + w) * 1024 + lane * 16;
      asm volatile("global_store_dwordx4 %0, %1, off sc1" :: "v"(dst), "v"(q) : "memory");
      asm volatile("s_waitcnt vmcnt(0)" ::: "memory");
      if (lane == 0) {
        int* tp = tags + ((size_t)t * 32 + w) * 4 + cw;
        int val = t + 1;
        asm volatile("global_store_dword %0, %1, off sc1" :: "v"(tp), "v"(val) : "memory");
      }
      // h_seq[:, t+1, w*32..+32): full-line f32 writes, off critical path
      int b2 = cw * 16 + (lane >> 2), sg = lane & 3;
      float* hd = out_hseq + ((size_t)b2 * 2048 + (size_t)(t + 1)) * 1024 + w * 32 + sg * 8;
      *(f32x4_t*)hd       = *(const f32x4_t*)(hs + b2 * 36 + sg * 8);
      *(f32x4_t*)(hd + 4) = *(const f32x4_t*)(hs + b2 * 36 + sg * 8 + 4);
    }
  }
}

// ---------------------------- launch ----------------------------

extern "C" void kernel_launch(void* const* d_in, const int* in_sizes, int n_in,
                              void* d_out, int out_size, void* d_ws, size_t ws_size,
                              hipStream_t stream) {
  const float* initial_state = (const float*)d_in[0];
  const float* rnn_input     = (const float*)d_in[1];
  const float* enc_w0        = (const float*)d_in[2];
  const float* enc_b0        = (const float*)d_in[3];
  const float* enc_w1        = (const float*)d_in[4];
  const float* enc_b1        = (const float*)d_in[5];
  const float* enc_w2        = (const float*)d_in[6];
  const float* enc_b2        = (const float*)d_in[7];
  const float* w_ih          = (const float*)d_in[8];
  const float* w_hh          = (const float*)d_in[9];
  const float* bias          = (const float*)d_in[10];

  char* ws = (char*)d_ws;
  int*            tags  = (int*)(ws + WS_TAGS);
  unsigned short* hbuf  = (unsigned short*)(ws + WS_HBUF);
  unsigned short* Wshuf = (unsigned short*)(ws + WS_WSHUF);
  unsigned short* WaugI = (unsigned short*)(ws + WS_WAUG);
  unsigned short* Xhat  = (unsigned short*)(ws + WS_XHAT);
  float*          h1    = (float*)(ws + WS_H1);
  float*          h2    = (float*)(ws + WS_H2);
  float*          out   = (float*)d_out;

  hipMemsetAsync(tags, 0, 1048576, stream);
  flumen_enc1<<<64, 512, 0, stream>>>(initial_state, enc_w0, enc_b0, h1);
  flumen_enc2<<<8, 512, 0, stream>>>(h1, enc_w1, enc_b1, h2);
  flumen_enc3<<<16, 512, 0, stream>>>(h2, enc_w2, enc_b2, out, hbuf);
  flumen_wshuf<<<1024, 512, 0, stream>>>(w_hh, Wshuf);
  flumen_waugi<<<32, 512, 0, stream>>>(w_ih, bias, WaugI);
  flumen_convx<<<2048, 512, 0, stream>>>(rnn_input, Xhat);
  flumen_lstm<<<32, 512, 0, stream>>>(Wshuf, WaugI, Xhat, hbuf, tags, out);
}

// Round 8
// 22973.433 us; speedup vs baseline: 2.1309x; 2.1309x over previous
//
#include <hip/hip_runtime.h>
#include <hip/hip_bf16.h>
#include <cstdint>
#include <cstddef>

// ---------------------------------------------------------------------------
// FlumenHead: encoder MLP (32->512->512->1024) + 2048-step LSTM (D=9, F=1024)
// v7b = v7 with the global_store_byte operand widened to u32 (compile fix).
//  - v5's proven per-wave shape (1 M-tile, Apin[32]=128 regs -> AGPR half)
//  - v6's proven conflict-free fragment-linear LDS (identity-copy fill)
//  - 64 CUs (WG = 16 features), wave = (M-tile, batch-half): each wave reads
//    only half the B image (per-CU LDS read halved vs v5)
//  - byte-tags: 4 helper waves write 4 bytes of one tag word per WG.
// ---------------------------------------------------------------------------

typedef __bf16 bf16x8_t __attribute__((ext_vector_type(8)));
typedef float f32x4_t __attribute__((ext_vector_type(4)));
typedef int   i32x4_t __attribute__((ext_vector_type(4)));
typedef unsigned long long u64_t;
typedef unsigned long long u64x2_t __attribute__((ext_vector_type(2)));
typedef unsigned short u16x4_t __attribute__((ext_vector_type(4)));

// workspace layout (bytes); total ~18.1 MB
#define WS_TAGS    0          // u32 tags[2048][64] (4 bytes per (t,wg)) 512 KB
#define WS_HBUF    524288     // u16 hbuf[2][128 blk][64 ln][8] bf16    256 KB
#define WS_WSHUF   786432     // u16 Wshuf[256 mt][32 kt][64 ln][8]       8 MB
#define WS_WAUG    9175040    // u16 WaugI[256 mt][64 ln][8]            256 KB
#define WS_XHAT    9437184    // u16 Xhat[2048 t][64 b][32] bf16          8 MB
#define WS_H1      17825792   // f32 h1[64][512]                        128 KB
#define WS_H2      17956864   // f32 h2[64][512]                        128 KB

__device__ __forceinline__ unsigned short f2bf(float f) {
  unsigned int u = __float_as_uint(f);
  u = (u + 0x7fffu + ((u >> 16) & 1u)) >> 16;   // RNE
  return (unsigned short)u;
}
__device__ __forceinline__ float sigm(float x) { return 1.f / (1.f + __expf(-x)); }
__device__ __forceinline__ float tanh_f(float x) {
  float e = __expf(-2.f * fabsf(x));
  float r = (1.f - e) / (1.f + e);
  return copysignf(r, x);
}

// ---------------------------- encoder ----------------------------

__global__ void flumen_enc1(const float* __restrict__ x, const float* __restrict__ W,
                            const float* __restrict__ b, float* __restrict__ h1) {
  const int bb = blockIdx.x;   // batch 0..63
  const int o  = threadIdx.x;  // 0..511
  const f32x4_t* xr = (const f32x4_t*)(x + bb * 32);
  const f32x4_t* wr = (const f32x4_t*)(W + o * 32);
  float acc = b[o];
#pragma unroll
  for (int q = 0; q < 8; ++q) {
    f32x4_t xv = xr[q], wv = wr[q];
    acc += xv[0] * wv[0] + xv[1] * wv[1] + xv[2] * wv[2] + xv[3] * wv[3];
  }
  h1[bb * 512 + o] = fmaxf(acc, 0.f);
}

__global__ void flumen_enc2(const float* __restrict__ in, const float* __restrict__ W,
                            const float* __restrict__ bv, float* __restrict__ outb) {
  __shared__ float s[64 * 256];
  const int tid = threadIdx.x;
  const int ol = tid & 63, bg = tid >> 6;
  const int o = blockIdx.x * 64 + ol;
  float bias = bv[o];
  float acc[8];
#pragma unroll
  for (int q = 0; q < 8; ++q) acc[q] = bias;
  for (int p = 0; p < 2; ++p) {
    __syncthreads();
    for (int i = tid; i < 4096; i += 512) {
      int flat = i * 4;
      int bb = flat >> 8, kk = flat & 255;
      *(f32x4_t*)(s + flat) = *(const f32x4_t*)(in + bb * 512 + p * 256 + kk);
    }
    __syncthreads();
    for (int kk = 0; kk < 256; kk += 4) {
      f32x4_t wv = *(const f32x4_t*)(W + o * 512 + p * 256 + kk);
#pragma unroll
      for (int j = 0; j < 4; ++j) {
        float wj = wv[j];
#pragma unroll
        for (int q = 0; q < 8; ++q)
          acc[q] += wj * s[(bg * 8 + q) * 256 + kk + j];
      }
    }
  }
#pragma unroll
  for (int q = 0; q < 8; ++q)
    outb[(bg * 8 + q) * 512 + o] = fmaxf(acc[q], 0.f);
}

__global__ void flumen_enc3(const float* __restrict__ in, const float* __restrict__ W,
                            const float* __restrict__ bv, float* __restrict__ dout,
                            unsigned short* __restrict__ hbuf) {
  __shared__ float s[64 * 256];
  const int tid = threadIdx.x;
  const int ol = tid & 63, bg = tid >> 6;
  const int o = blockIdx.x * 64 + ol;   // 0..1023
  float bias = bv[o];
  float acc[8];
#pragma unroll
  for (int q = 0; q < 8; ++q) acc[q] = bias;
  for (int p = 0; p < 2; ++p) {
    __syncthreads();
    for (int i = tid; i < 4096; i += 512) {
      int flat = i * 4;
      int bb = flat >> 8, kk = flat & 255;
      *(f32x4_t*)(s + flat) = *(const f32x4_t*)(in + bb * 512 + p * 256 + kk);
    }
    __syncthreads();
    for (int kk = 0; kk < 256; kk += 4) {
      f32x4_t wv = *(const f32x4_t*)(W + o * 512 + p * 256 + kk);
#pragma unroll
      for (int j = 0; j < 4; ++j) {
        float wj = wv[j];
#pragma unroll
        for (int q = 0; q < 8; ++q)
          acc[q] += wj * s[(bg * 8 + q) * 256 + kk + j];
      }
    }
  }
  float* out_hseq = dout + 65536;
#pragma unroll
  for (int q = 0; q < 8; ++q) {
    int bb = bg * 8 + q;
    float v = acc[q];
    out_hseq[(size_t)bb * 2097152 + o] = v;   // h_seq[b][0][o]
    // fragment-linear hbuf[0]: block = (b>>4)*32 + (o>>5),
    // lane = ((o>>3)&3)*16 + (b&15), e = o&7
    int blk  = (bb >> 4) * 32 + (o >> 5);
    int lane = ((o >> 3) & 3) * 16 + (bb & 15);
    hbuf[blk * 512 + lane * 8 + (o & 7)] = f2bf(v);
  }
}

// ---------------------------- precompute ----------------------------

// Gate-interleaved A fragments: Wshuf[mt][kt][lane][8],
// A row r = lane&15 -> gate g = r&3, feature f = mt*4 + (r>>2);
// k = kt*32 + (lane>>4)*8 + e; src = w_hh[(g*1024+f)*1024 + k].
__global__ void flumen_wshuf(const float* __restrict__ src, unsigned short* __restrict__ dst) {
  int idx = blockIdx.x * 512 + threadIdx.x;      // 0..524287
  int lane = idx & 63, kt = (idx >> 6) & 31, mt = idx >> 11;
  int r = lane & 15;
  int g = r & 3, f = mt * 4 + (r >> 2);
  int k0 = kt * 32 + (lane >> 4) * 8;
  const float* sp = src + (size_t)(g * 1024 + f) * 1024 + k0;
  f32x4_t v0 = *(const f32x4_t*)(sp);
  f32x4_t v1 = *(const f32x4_t*)(sp + 4);
  u16x4_t o0, o1;
#pragma unroll
  for (int j = 0; j < 4; ++j) { o0[j] = f2bf(v0[j]); o1[j] = f2bf(v1[j]); }
  u16x4_t* dp = (u16x4_t*)(dst + (size_t)idx * 8);
  dp[0] = o0; dp[1] = o1;
}

// Gate-interleaved augmented fragments: WaugI[mt][lane][8], K=32:
// k<9 -> w_ih[(g*1024+f)*9+k], k==9 -> bias[g*1024+f], else 0.
__global__ void flumen_waugi(const float* __restrict__ wih, const float* __restrict__ bias,
                             unsigned short* __restrict__ dst) {
  int idx = blockIdx.x * 512 + threadIdx.x;      // 0..16383
  int lane = idx & 63, mt = idx >> 6;
  int r = lane & 15;
  int g = r & 3, f = mt * 4 + (r >> 2);
  int k0 = (lane >> 4) * 8;
  unsigned short o[8];
#pragma unroll
  for (int j = 0; j < 8; ++j) {
    int k = k0 + j;
    float v = (k < 9) ? wih[(size_t)(g * 1024 + f) * 9 + k]
                      : (k == 9 ? bias[g * 1024 + f] : 0.f);
    o[j] = f2bf(v);
  }
  u16x4_t* dp = (u16x4_t*)(dst + (size_t)idx * 8);
  dp[0] = *(u16x4_t*)&o[0];
  dp[1] = *(u16x4_t*)&o[4];
}

// Xhat[t][b][0..8]=x[b][t][:], [9]=1.0, rest 0. grid=2048.
__global__ void flumen_convx(const float* __restrict__ xin, unsigned short* __restrict__ dst) {
  int i = (blockIdx.x * 512 + threadIdx.x) * 4;   // elem index, 4 at a time
  int b = i >> 16, t = (i >> 5) & 2047, c0 = i & 31;
  u16x4_t o;
#pragma unroll
  for (int j = 0; j < 4; ++j) {
    int cc = c0 + j;
    float v = (cc < 9) ? xin[((size_t)b * 2048 + t) * 9 + cc] : (cc == 9 ? 1.f : 0.f);
    o[j] = f2bf(v);
  }
  *(u16x4_t*)(dst + ((size_t)t * 64 + b) * 32 + c0) = o;
}

// ---------------------------- persistent LSTM ----------------------------
// 64 WGs x 512 thr, 1 WG/CU (136 KB LDS). WG w owns features [16w,16w+16)
// = M-tiles w*4..w*4+4 (gate-interleaved, 16 rows each).
// Wave = mt_local + 4*nh: mt_local 0..3 picks M-tile, nh 0..1 picks batch
// half [32nh, 32nh+32). Apin[32] = 128 regs/wave (AGPR half of 256 budget).
// B image fragment-linear in hbuf AND LDS (identity fill, conflict-free);
// each wave reads only its nh half (64 x ds_read_b128 per step).
// Cell lane-local: acc[n2][j] = gate j of (batch nh*32+n2*16+l15,
// feature w*16 + mt_local*4 + l4).
// Publish: 4 helper-role waves (nh==1) pack 512B chunks; byte-tags
// (tags[t][w] dword, byte hw, value 0x80|((t+1)&0x7f)).
__global__ __launch_bounds__(512, 1) void flumen_lstm(
    const unsigned short* __restrict__ Wshuf,
    const unsigned short* __restrict__ WaugI,
    const unsigned short* __restrict__ Xhat,
    unsigned short* hbuf, unsigned int* tags, float* out)
{
  __shared__ __align__(16) char smem[136192];
  char*  h_lds = smem;                           // 128KB fragment-linear B
  float* hs    = (float*)(smem + 131072);        // [64][20] f32 staging

  float* out_hlast = out;
  float* out_hseq  = out + 65536;
  const int w    = blockIdx.x;       // 0..63
  const int tid  = threadIdx.x;
  const int lane = tid & 63;
  const int wave = tid >> 6;         // 0..7
  const int mt_local = wave & 3;
  const int nh   = wave >> 2;        // batch half
  const int l15  = lane & 15;
  const int l4   = lane >> 4;

  // pinned A: 1 M-tile, 32 K-frags = 128 regs, t-invariant
  const int mt = w * 4 + mt_local;
  bf16x8_t Apin[32];
  {
    const char* ap = (const char*)Wshuf + (size_t)mt * 32768 + lane * 16;
#pragma unroll
    for (int kt = 0; kt < 32; ++kt)
      Apin[kt] = *(const bf16x8_t*)(ap + kt * 1024);
  }
  const bf16x8_t wfragI =
      *(const bf16x8_t*)((const char*)WaugI + (size_t)mt * 1024 + lane * 16);

  float carr[2] = {0.f, 0.f};

  for (int t = 0; t < 2048; ++t) {
    // x fragments + aug MFMAs (independent of h_t; hide under poll)
    f32x4_t acc[2];
#pragma unroll
    for (int n2 = 0; n2 < 2; ++n2) {
      const int batch = nh * 32 + n2 * 16 + l15;
      bf16x8_t xf = *(const bf16x8_t*)(Xhat + ((size_t)t * 64 + batch) * 32 + l4 * 8);
      acc[n2] = __builtin_amdgcn_mfma_f32_16x16x32_bf16(
          wfragI, xf, (f32x4_t){0.f, 0.f, 0.f, 0.f}, 0, 0, 0);
    }

    if (t > 0) {
      // poll: lane = producer wg; all 4 tag bytes must equal 0x80|(t&0x7f)
      const unsigned int pat = (0x80u | ((unsigned)t & 0x7fu)) * 0x01010101u;
      const char* tp = (const char*)tags + ((size_t)(t - 1) * 64 + lane) * 4;
      int iter = 0;
      while (true) {
        unsigned int tv;
        asm volatile("global_load_dword %0, %1, off sc1\n\ts_waitcnt vmcnt(0)"
                     : "=v"(tv) : "v"(tp) : "memory");
        if (__all(tv == pat) || ++iter >= (1 << 20)) break;
      }
      __builtin_amdgcn_sched_barrier(0);
    }

    // identity fill: hbuf[t&1] -> h_lds (coalesced, conflict-free)
    {
      const char* src0 = (const char*)hbuf + (size_t)((t & 1) * 131072) + tid * 16;
      f32x4_t v[8];
#pragma unroll
      for (int i = 0; i < 8; ++i)
        asm volatile("global_load_dwordx4 %0, %1, off sc1"
                     : "=v"(v[i]) : "v"(src0 + i * 8192) : "memory");
      asm volatile("s_waitcnt vmcnt(0)" ::: "memory");
      __builtin_amdgcn_sched_barrier(0);
#pragma unroll
      for (int i = 0; i < 8; ++i)
        *(f32x4_t*)(h_lds + tid * 16 + i * 8192) = v[i];
#pragma unroll
      for (int i = 0; i < 8; ++i)
        asm volatile("global_load_dwordx4 %0, %1, off sc1"
                     : "=v"(v[i]) : "v"(src0 + (i + 8) * 8192) : "memory");
      asm volatile("s_waitcnt vmcnt(0)" ::: "memory");
      __builtin_amdgcn_sched_barrier(0);
#pragma unroll
      for (int i = 0; i < 8; ++i)
        *(f32x4_t*)(h_lds + tid * 16 + (i + 8) * 8192) = v[i];
    }
    __syncthreads();

    // K loop: this wave's batch half only (2 n-tiles x 32 kt)
#pragma unroll
    for (int n2 = 0; n2 < 2; ++n2) {
      const char* bb = h_lds + (nh * 2 + n2) * 32768 + lane * 16;
#pragma unroll
      for (int kt = 0; kt < 32; ++kt) {
        bf16x8_t bf = *(const bf16x8_t*)(bb + kt * 1024);
        acc[n2] = __builtin_amdgcn_mfma_f32_16x16x32_bf16(Apin[kt], bf, acc[n2], 0, 0, 0);
      }
    }

    // lane-local cell: acc[n2] = {i,f,g,o} of (batch, feat w*16+mt_local*4+l4)
#pragma unroll
    for (int n2 = 0; n2 < 2; ++n2) {
      const int batch = nh * 32 + n2 * 16 + l15;
      float c = sigm(acc[n2][1]) * carr[n2] + sigm(acc[n2][0]) * tanh_f(acc[n2][2]);
      carr[n2] = c;
      float h = sigm(acc[n2][3]) * tanh_f(c);
      if (t < 2047) {
        hs[batch * 20 + mt_local * 4 + l4] = h;
      } else {
        out_hlast[batch * 1024 + w * 16 + mt_local * 4 + l4] = h;
      }
    }
    __syncthreads();

    if (nh == 1 && t < 2047) {
      // helper role: wave 4+hw (hw = mt_local) publishes n-block hw.
      const int hw = mt_local;
      if (lane < 32) {
        // pack 16B bf16: h[hw*16+l15][w*16 + l4*8 .. +8]
        const float* hp = hs + (hw * 16 + l15) * 20 + l4 * 8;
        f32x4_t u0 = *(const f32x4_t*)(hp);
        f32x4_t u1 = *(const f32x4_t*)(hp + 4);
        u64_t lo = (u64_t)f2bf(u0[0]) | ((u64_t)f2bf(u0[1]) << 16)
                 | ((u64_t)f2bf(u0[2]) << 32) | ((u64_t)f2bf(u0[3]) << 48);
        u64_t hi = (u64_t)f2bf(u1[0]) | ((u64_t)f2bf(u1[1]) << 16)
                 | ((u64_t)f2bf(u1[2]) << 32) | ((u64_t)f2bf(u1[3]) << 48);
        u64x2_t q = {lo, hi};
        // block (n=hw, kt=w>>1), half (w&1): byte = blk*1024 + (w&1)*512 + lane*16
        char* dst = (char*)hbuf + (size_t)(((t + 1) & 1) * 131072)
                  + (hw * 32 + (w >> 1)) * 1024 + (w & 1) * 512 + lane * 16;
        asm volatile("global_store_dwordx4 %0, %1, off sc1" :: "v"(dst), "v"(q) : "memory");
      }
      asm volatile("s_waitcnt vmcnt(0)" ::: "memory");
      if (lane == 0) {
        unsigned int val = 0x80u | ((unsigned)(t + 1) & 0x7fu);  // u32 for "v" constraint
        char* tp = (char*)tags + ((size_t)t * 64 + w) * 4 + hw;
        asm volatile("global_store_byte %0, %1, off sc1" :: "v"(tp), "v"(val) : "memory");
      }
      // h_seq[:, t+1, w*16..+16): 64B rows, off critical path
      {
        int b2 = hw * 16 + (lane >> 2), sg = lane & 3;
        float* hd = out_hseq + ((size_t)b2 * 2048 + (size_t)(t + 1)) * 1024 + w * 16 + sg * 4;
        *(f32x4_t*)hd = *(const f32x4_t*)(hs + b2 * 20 + sg * 4);
      }
    }
  }
}

// ---------------------------- launch ----------------------------

extern "C" void kernel_launch(void* const* d_in, const int* in_sizes, int n_in,
                              void* d_out, int out_size, void* d_ws, size_t ws_size,
                              hipStream_t stream) {
  const float* initial_state = (const float*)d_in[0];
  const float* rnn_input     = (const float*)d_in[1];
  const float* enc_w0        = (const float*)d_in[2];
  const float* enc_b0        = (const float*)d_in[3];
  const float* enc_w1        = (const float*)d_in[4];
  const float* enc_b1        = (const float*)d_in[5];
  const float* enc_w2        = (const float*)d_in[6];
  const float* enc_b2        = (const float*)d_in[7];
  const float* w_ih          = (const float*)d_in[8];
  const float* w_hh          = (const float*)d_in[9];
  const float* bias          = (const float*)d_in[10];

  char* ws = (char*)d_ws;
  unsigned int*   tags  = (unsigned int*)(ws + WS_TAGS);
  unsigned short* hbuf  = (unsigned short*)(ws + WS_HBUF);
  unsigned short* Wshuf = (unsigned short*)(ws + WS_WSHUF);
  unsigned short* WaugI = (unsigned short*)(ws + WS_WAUG);
  unsigned short* Xhat  = (unsigned short*)(ws + WS_XHAT);
  float*          h1    = (float*)(ws + WS_H1);
  float*          h2    = (float*)(ws + WS_H2);
  float*          out   = (float*)d_out;

  (void)hipMemsetAsync(tags, 0, 524288, stream);
  flumen_enc1<<<64, 512, 0, stream>>>(initial_state, enc_w0, enc_b0, h1);
  flumen_enc2<<<8, 512, 0, stream>>>(h1, enc_w1, enc_b1, h2);
  flumen_enc3<<<16, 512, 0, stream>>>(h2, enc_w2, enc_b2, out, hbuf);
  flumen_wshuf<<<1024, 512, 0, stream>>>(w_hh, Wshuf);
  flumen_waugi<<<32, 512, 0, stream>>>(w_ih, bias, WaugI);
  flumen_convx<<<2048, 512, 0, stream>>>(rnn_input, Xhat);
  flumen_lstm<<<64, 512, 0, stream>>>(Wshuf, WaugI, Xhat, hbuf, tags, out);
}